// Round 1
// baseline (540.329 us; speedup 1.0000x reference)
//
#include <hip/hip_runtime.h>
#include <math.h>

#define BS 128   // threads per block; 64-row LDS column buffer = 32 KB -> 5 blocks/CU

__global__ __launch_bounds__(BS) void nerf_mlp_kernel(
    const float* __restrict__ x,
    const float* __restrict__ ws0, const float* __restrict__ ws1, const float* __restrict__ ws2,
    const float* __restrict__ wc0, const float* __restrict__ wc1, const float* __restrict__ wc2,
    const float* __restrict__ wc3,
    float* __restrict__ out, int n)
{
    // Per-thread activation column: act[row*BS + tid]. Each thread only ever
    // touches its own column -> no barriers needed. Row stride 128 floats ->
    // lanes hit banks tid%32 (2-way alias across wave64 = free).
    __shared__ float act[64 * BS];
    const int tid = threadIdx.x;
    const int i = blockIdx.x * BS + tid;
    if (i >= n) return;

    // ---- load input point (6 floats @ 8B-aligned) ----
    const float2* x2 = (const float2*)x;
    float2 p01 = x2[i * 3 + 0];
    float2 p2v0 = x2[i * 3 + 1];
    float2 v12 = x2[i * 3 + 2];
    const float p0 = p01.x, p1 = p01.y, p2 = p2v0.x;
    const float v0 = p2v0.y, v1 = v12.x, v2 = v12.y;

    // ---- sigma layer 0: 3 -> 64, relu (fully static) ----
#pragma unroll
    for (int j = 0; j < 64; ++j) {
        float a = p0 * ws0[0 * 64 + j];
        a = fmaf(p1, ws0[1 * 64 + j], a);
        a = fmaf(p2, ws0[2 * 64 + j], a);
        act[j * BS + tid] = fmaxf(a, 0.f);
    }

    // ---- sigma layer 1: 64 -> 64, relu ----
    {
        float acc[64];
#pragma unroll
        for (int j = 0; j < 64; ++j) acc[j] = 0.f;
        for (int k = 0; k < 64; ++k) {
            float a = act[k * BS + tid];           // ds_read, own column
#pragma unroll
            for (int j = 0; j < 64; ++j)
                acc[j] = fmaf(a, ws1[k * 64 + j], acc[j]);  // weight: uniform -> s_load
        }
#pragma unroll
        for (int j = 0; j < 64; ++j) act[j * BS + tid] = fmaxf(acc[j], 0.f);
    }

    // ---- sigma layer 2: 64 -> 16 (no relu) ----
    float h2[16];
    {
#pragma unroll
        for (int j = 0; j < 16; ++j) h2[j] = 0.f;
        for (int k = 0; k < 64; ++k) {
            float a = act[k * BS + tid];
#pragma unroll
            for (int j = 0; j < 16; ++j)
                h2[j] = fmaf(a, ws2[k * 16 + j], h2[j]);
        }
    }

    // sigma = softplus(h2[0]), numerically stable
    const float sx = h2[0];
    const float sigma = fmaxf(sx, 0.f) + log1pf(expf(-fabsf(sx)));

    // ---- color input: [views(3), geo_feat(15)] -> LDS rows 0..17 ----
    act[0 * BS + tid] = v0;
    act[1 * BS + tid] = v1;
    act[2 * BS + tid] = v2;
#pragma unroll
    for (int j = 0; j < 15; ++j) act[(3 + j) * BS + tid] = h2[1 + j];

    // ---- color layer 0: 18 -> 64, relu ----
    {
        float acc[64];
#pragma unroll
        for (int j = 0; j < 64; ++j) acc[j] = 0.f;
        for (int k = 0; k < 18; ++k) {
            float a = act[k * BS + tid];
#pragma unroll
            for (int j = 0; j < 64; ++j)
                acc[j] = fmaf(a, wc0[k * 64 + j], acc[j]);
        }
#pragma unroll
        for (int j = 0; j < 64; ++j) act[j * BS + tid] = fmaxf(acc[j], 0.f);
    }

    // ---- color layer 1: 64 -> 64, relu ----
    {
        float acc[64];
#pragma unroll
        for (int j = 0; j < 64; ++j) acc[j] = 0.f;
        for (int k = 0; k < 64; ++k) {
            float a = act[k * BS + tid];
#pragma unroll
            for (int j = 0; j < 64; ++j)
                acc[j] = fmaf(a, wc1[k * 64 + j], acc[j]);
        }
#pragma unroll
        for (int j = 0; j < 64; ++j) act[j * BS + tid] = fmaxf(acc[j], 0.f);
    }

    // ---- color layer 2: 64 -> 64, relu ----
    {
        float acc[64];
#pragma unroll
        for (int j = 0; j < 64; ++j) acc[j] = 0.f;
        for (int k = 0; k < 64; ++k) {
            float a = act[k * BS + tid];
#pragma unroll
            for (int j = 0; j < 64; ++j)
                acc[j] = fmaf(a, wc2[k * 64 + j], acc[j]);
        }
#pragma unroll
        for (int j = 0; j < 64; ++j) act[j * BS + tid] = fmaxf(acc[j], 0.f);
    }

    // ---- color layer 3: 64 -> 3 (static accumulators) ----
    {
        float c0 = 0.f, c1 = 0.f, c2 = 0.f;
        for (int k = 0; k < 64; ++k) {
            float a = act[k * BS + tid];
            c0 = fmaf(a, wc3[k * 3 + 0], c0);
            c1 = fmaf(a, wc3[k * 3 + 1], c1);
            c2 = fmaf(a, wc3[k * 3 + 2], c2);
        }
        float4 o = make_float4(c0, c1, c2, sigma);
        ((float4*)out)[i] = o;   // coalesced 16B store
    }
}

extern "C" void kernel_launch(void* const* d_in, const int* in_sizes, int n_in,
                              void* d_out, int out_size, void* d_ws, size_t ws_size,
                              hipStream_t stream) {
    const float* x   = (const float*)d_in[0];
    const float* ws0 = (const float*)d_in[1];
    const float* ws1 = (const float*)d_in[2];
    const float* ws2 = (const float*)d_in[3];
    const float* wc0 = (const float*)d_in[4];
    const float* wc1 = (const float*)d_in[5];
    const float* wc2 = (const float*)d_in[6];
    const float* wc3 = (const float*)d_in[7];
    float* out = (float*)d_out;

    const int n = in_sizes[0] / 6;
    const int grid = (n + BS - 1) / BS;
    nerf_mlp_kernel<<<grid, BS, 0, stream>>>(x, ws0, ws1, ws2, wc0, wc1, wc2, wc3, out, n);
}

// Round 2
// 183.985 us; speedup vs baseline: 2.9368x; 2.9368x over previous
//
#include <hip/hip_runtime.h>
#include <math.h>
#include <stdint.h>

typedef short bf16x8 __attribute__((ext_vector_type(8)));   // 8 bf16 (4 VGPRs), raw bits
typedef float f32x4 __attribute__((ext_vector_type(4)));

#define NFRAGS 36
#define TILES 3            // point-tiles (16 pts) per wave per pass
#define NWAVES 4
#define BS (NWAVES * 64)
#define PTS_PER_BLOCK (NWAVES * TILES * 16)   // 192
#define ACT_BYTES 2048     // per (wave,tile): 8 chunk-rows x 16 pts x 16B

// RNE float -> bf16 bits (finite inputs only)
__device__ __forceinline__ uint32_t f2bf(float f) {
    uint32_t u = __float_as_uint(f);
    return (u + 0x7FFFu + ((u >> 16) & 1u)) >> 16;
}

__global__ __launch_bounds__(BS) void nerf_mfma_kernel(
    const float* __restrict__ xin,
    const float* __restrict__ ws0, const float* __restrict__ ws1, const float* __restrict__ ws2,
    const float* __restrict__ wc0, const float* __restrict__ wc1, const float* __restrict__ wc2,
    const float* __restrict__ wc3,
    float* __restrict__ outp, int n)
{
    // LDS: 36 KB weight A-fragments (fragment-linear) + 24 KB wave-private act scratch
    __shared__ __align__(16) char smem[NFRAGS * 1024 + NWAVES * TILES * ACT_BYTES];
    char* wlds = smem;
    char* apool = smem + NFRAGS * 1024;

    const int tid = threadIdx.x;
    const int wv = tid >> 6, lane = tid & 63;
    const int p = lane & 15, q = lane >> 4;

    // ---- stage all weights as bf16 A-fragments: Wt[f_out][f_in], frag-linear ----
    for (int idx = tid; idx < NFRAGS * 64; idx += BS) {
        const int F = idx >> 6, cl = idx & 63;
        const int cm = cl & 15, cq = cl >> 4;
        const float* w; int IN, OUT, mt, ks;
        if (F < 4)       { w = ws0; IN = 3;  OUT = 64; mt = F;          ks = 0; }
        else if (F < 12) { w = ws1; IN = 64; OUT = 64; mt = (F-4) >> 1;  ks = (F-4) & 1; }
        else if (F < 14) { w = ws2; IN = 64; OUT = 16; mt = 0;          ks = F - 12; }
        else if (F < 18) { w = wc0; IN = 18; OUT = 64; mt = F - 14;     ks = 0; }
        else if (F < 26) { w = wc1; IN = 64; OUT = 64; mt = (F-18) >> 1; ks = (F-18) & 1; }
        else if (F < 34) { w = wc2; IN = 64; OUT = 64; mt = (F-26) >> 1; ks = (F-26) & 1; }
        else             { w = wc3; IN = 64; OUT = 3;  mt = 0;          ks = F - 34; }
        const int fo = mt * 16 + cm;
        uint32_t pk[4];
#pragma unroll
        for (int jj = 0; jj < 4; ++jj) {
            const int k0 = ks * 32 + cq * 8 + jj * 2;
            float a = 0.f, b = 0.f;
            if (fo < OUT) {
                if (k0 < IN)     a = w[k0 * OUT + fo];
                if (k0 + 1 < IN) b = w[(k0 + 1) * OUT + fo];
            }
            pk[jj] = f2bf(a) | (f2bf(b) << 16);
        }
        *((uint4*)(wlds + F * 1024 + cl * 16)) = make_uint4(pk[0], pk[1], pk[2], pk[3]);
    }
    __syncthreads();

    char* act[TILES];
#pragma unroll
    for (int t = 0; t < TILES; ++t) act[t] = apool + (wv * TILES + t) * ACT_BYTES;

    const f32x4 z4 = {0.f, 0.f, 0.f, 0.f};

    auto ldA = [&](int F) -> bf16x8 {
        return *((const bf16x8*)(wlds + F * 1024 + lane * 16));
    };
    auto ldB = [&](char* a, int s) -> bf16x8 {
        return *((const bf16x8*)(a + ((s * 4 + q) * 16 + p) * 16));
    };
    // write 16x64 D (4 m-tiles) as relu'd bf16 into chunk layout: feat f=mt*16+q*4+r
    auto stH = [&](char* a, const f32x4* d) {
#pragma unroll
        for (int mt = 0; mt < 4; ++mt) {
            const float e0 = fmaxf(d[mt][0], 0.f), e1 = fmaxf(d[mt][1], 0.f);
            const float e2 = fmaxf(d[mt][2], 0.f), e3 = fmaxf(d[mt][3], 0.f);
            const uint32_t lo = f2bf(e0) | (f2bf(e1) << 16);
            const uint32_t hi = f2bf(e2) | (f2bf(e3) << 16);
            *((uint2*)(a + ((mt * 2 + (q >> 1)) * 16 + p) * 16 + (q & 1) * 8)) =
                make_uint2(lo, hi);
        }
    };

    const int stride_pts = gridDim.x * PTS_PER_BLOCK;
    for (int base = blockIdx.x * PTS_PER_BLOCK; base < n; base += stride_pts) {
        // ---- input staging: lane (p,q) handles tile q (q<TILES), point p ----
        float v0 = 0.f, v1 = 0.f, v2 = 0.f;
        if (q < TILES) {
            const int pi = base + wv * (TILES * 16) + q * 16 + p;
            char* a = apool + (wv * TILES + q) * ACT_BYTES;
            const uint4 z = make_uint4(0, 0, 0, 0);
            if (pi < n) {
                const float* xp = xin + (size_t)pi * 6;
                const float2 a01 = *((const float2*)xp);
                const float2 a23 = *((const float2*)(xp + 2));
                const float2 a45 = *((const float2*)(xp + 4));
                v0 = a23.y; v1 = a45.x; v2 = a45.y;
                uint4 b0;
                b0.x = f2bf(a01.x) | (f2bf(a01.y) << 16);
                b0.y = f2bf(a23.x);            // {x2, 0}
                b0.z = 0u; b0.w = 0u;
                *((uint4*)(a + p * 16)) = b0;  // chunk0 row p: k=0..7
            } else {
                *((uint4*)(a + p * 16)) = z;
            }
            // zero chunks 1..3 (k=8..31)
            *((uint4*)(a + 256 + p * 48)) = z;
            *((uint4*)(a + 256 + p * 48 + 16)) = z;
            *((uint4*)(a + 256 + p * 48 + 32)) = z;
        }

        // ---- L0: sigma layer 0 (3->64), frags 0..3, K=32 single step ----
        {
            bf16x8 A0 = ldA(0), A1 = ldA(1), A2 = ldA(2), A3 = ldA(3);
#pragma unroll
            for (int t = 0; t < TILES; ++t) {
                bf16x8 b = ldB(act[t], 0);
                f32x4 d[4];
                d[0] = __builtin_amdgcn_mfma_f32_16x16x32_bf16(A0, b, z4, 0, 0, 0);
                d[1] = __builtin_amdgcn_mfma_f32_16x16x32_bf16(A1, b, z4, 0, 0, 0);
                d[2] = __builtin_amdgcn_mfma_f32_16x16x32_bf16(A2, b, z4, 0, 0, 0);
                d[3] = __builtin_amdgcn_mfma_f32_16x16x32_bf16(A3, b, z4, 0, 0, 0);
                stH(act[t], d);
            }
        }

        // 64->64 layer (relu): frags fb..fb+7 ordered (m_tile*2 + k_step)
        auto layer64 = [&](int fb) {
            bf16x8 A[8];
#pragma unroll
            for (int i = 0; i < 8; ++i) A[i] = ldA(fb + i);
#pragma unroll
            for (int t = 0; t < TILES; ++t) {
                bf16x8 b0 = ldB(act[t], 0), b1 = ldB(act[t], 1);
                f32x4 d[4];
#pragma unroll
                for (int mt = 0; mt < 4; ++mt) {
                    f32x4 acc = __builtin_amdgcn_mfma_f32_16x16x32_bf16(A[mt*2],   b0, z4,  0, 0, 0);
                    d[mt]     = __builtin_amdgcn_mfma_f32_16x16x32_bf16(A[mt*2+1], b1, acc, 0, 0, 0);
                }
                stH(act[t], d);
            }
        };

        // ---- L1: sigma layer 1 (64->64) ----
        layer64(4);

        // ---- L2: ws2 (64->16), sigma + color-input staging ----
        float sig[TILES];
        {
            bf16x8 A0 = ldA(12), A1 = ldA(13);
#pragma unroll
            for (int t = 0; t < TILES; ++t) {
                bf16x8 b0 = ldB(act[t], 0), b1 = ldB(act[t], 1);
                f32x4 acc = __builtin_amdgcn_mfma_f32_16x16x32_bf16(A0, b0, z4,  0, 0, 0);
                f32x4 d   = __builtin_amdgcn_mfma_f32_16x16x32_bf16(A1, b1, acc, 0, 0, 0);
                // sigma = softplus(feat0) -- valid on q==0 lanes
                const float zz = d[0];
                sig[t] = fmaxf(zz, 0.f) + log1pf(expf(-fabsf(zz)));
                char* a = act[t];
                // zero chunks 2,3 (color k=16..31) BEFORE geo writes (in-order DS)
                *((uint2*)(a + 512 + lane * 8)) = make_uint2(0u, 0u);
                // views at color k=0..2 (stashed by the lane whose staging tile q==t)
                if (q == t) {
                    *((uint32_t*)(a + p * 16))     = f2bf(v0) | (f2bf(v1) << 16);
                    *((uint16_t*)(a + p * 16 + 4)) = (uint16_t)f2bf(v2);
                }
                // geo_feat: lane's D feats f=q*4+r (f>=1) -> color k=f+2
                if (q == 0) {
                    *((uint16_t*)(a + p * 16 + 6)) = (uint16_t)f2bf(d[1]);        // k=3
                    *((uint32_t*)(a + p * 16 + 8)) = f2bf(d[2]) | (f2bf(d[3]) << 16); // k=4,5
                } else {
                    const int k0 = q * 4 + 2;
                    *((uint32_t*)(a + ((k0 >> 3) * 16 + p) * 16 + (k0 & 7) * 2)) =
                        f2bf(d[0]) | (f2bf(d[1]) << 16);
                    const int k2 = k0 + 2;
                    *((uint32_t*)(a + ((k2 >> 3) * 16 + p) * 16 + (k2 & 7) * 2)) =
                        f2bf(d[2]) | (f2bf(d[3]) << 16);
                }
            }
        }

        // ---- L3: wc0 (18->64 padded to 32), frags 14..17, K=32 ----
        {
            bf16x8 A0 = ldA(14), A1 = ldA(15), A2 = ldA(16), A3 = ldA(17);
#pragma unroll
            for (int t = 0; t < TILES; ++t) {
                bf16x8 b = ldB(act[t], 0);
                f32x4 d[4];
                d[0] = __builtin_amdgcn_mfma_f32_16x16x32_bf16(A0, b, z4, 0, 0, 0);
                d[1] = __builtin_amdgcn_mfma_f32_16x16x32_bf16(A1, b, z4, 0, 0, 0);
                d[2] = __builtin_amdgcn_mfma_f32_16x16x32_bf16(A2, b, z4, 0, 0, 0);
                d[3] = __builtin_amdgcn_mfma_f32_16x16x32_bf16(A3, b, z4, 0, 0, 0);
                stH(act[t], d);
            }
        }

        // ---- L4, L5: wc1, wc2 (64->64) ----
        layer64(18);
        layer64(26);

        // ---- L6: wc3 (64->3), frags 34,35; output ----
        {
            bf16x8 A0 = ldA(34), A1 = ldA(35);
#pragma unroll
            for (int t = 0; t < TILES; ++t) {
                bf16x8 b0 = ldB(act[t], 0), b1 = ldB(act[t], 1);
                f32x4 acc = __builtin_amdgcn_mfma_f32_16x16x32_bf16(A0, b0, z4,  0, 0, 0);
                f32x4 d   = __builtin_amdgcn_mfma_f32_16x16x32_bf16(A1, b1, acc, 0, 0, 0);
                if (q == 0) {
                    const int pt = base + wv * (TILES * 16) + t * 16 + p;
                    if (pt < n) {
                        float4 o = make_float4(d[0], d[1], d[2], sig[t]);
                        *((float4*)(outp + (size_t)pt * 4)) = o;
                    }
                }
            }
        }
    }
}

extern "C" void kernel_launch(void* const* d_in, const int* in_sizes, int n_in,
                              void* d_out, int out_size, void* d_ws, size_t ws_size,
                              hipStream_t stream) {
    const float* x   = (const float*)d_in[0];
    const float* ws0 = (const float*)d_in[1];
    const float* ws1 = (const float*)d_in[2];
    const float* ws2 = (const float*)d_in[3];
    const float* wc0 = (const float*)d_in[4];
    const float* wc1 = (const float*)d_in[5];
    const float* wc2 = (const float*)d_in[6];
    const float* wc3 = (const float*)d_in[7];
    float* out = (float*)d_out;

    const int n = in_sizes[0] / 6;
    int grid = (n + PTS_PER_BLOCK - 1) / PTS_PER_BLOCK;
    if (grid > 1024) grid = 1024;
    nerf_mfma_kernel<<<grid, BS, 0, stream>>>(x, ws0, ws1, ws2, wc0, wc1, wc2, wc3, out, n);
}

// Round 3
// 135.458 us; speedup vs baseline: 3.9889x; 1.3582x over previous
//
#include <hip/hip_runtime.h>
#include <math.h>
#include <stdint.h>

typedef short bf16x8 __attribute__((ext_vector_type(8)));   // 8 bf16 (4 VGPRs)
typedef float f32x4 __attribute__((ext_vector_type(4)));

#define NFRAGS 36
#define T 4                 // point-tiles (16 pts) per wave
#define NW 4                // waves per block
#define BS 256
#define PTS_BLK (NW * T * 16)   // 256 points per block

// RNE float -> bf16 bits (prologue only)
__device__ __forceinline__ uint32_t f2bf_rne(float f) {
    uint32_t u = __float_as_uint(f);
    return (u + 0x7FFFu + ((u >> 16) & 1u)) >> 16;
}
// round-half-up pack of two f32 -> packed bf16 {lo=a, hi=b}: 2 adds + 1 v_perm
__device__ __forceinline__ uint32_t pk2(float a, float b) {
    return __builtin_amdgcn_perm(__float_as_uint(b) + 0x8000u,
                                 __float_as_uint(a) + 0x8000u, 0x07060302u);
}
__device__ __forceinline__ uint32_t pk2r(float a, float b) {   // + relu
    return pk2(fmaxf(a, 0.f), fmaxf(b, 0.f));
}
__device__ __forceinline__ uint16_t bfu(float v) {
    return (uint16_t)((__float_as_uint(v) + 0x8000u) >> 16);
}
// storage permutation: swap feat bits [5:4] <-> [3:2]  (involution)
__device__ __forceinline__ int sperm(int k) {
    return (k & 3) | (((k >> 2) & 3) << 4) | (((k >> 4) & 3) << 2);
}

// ---------------- prologue: pack 36 A-fragments into d_ws ----------------
__global__ void pack_weights(const float* __restrict__ ws0, const float* __restrict__ ws1,
                             const float* __restrict__ ws2, const float* __restrict__ wc0,
                             const float* __restrict__ wc1, const float* __restrict__ wc2,
                             const float* __restrict__ wc3, uint4* __restrict__ wpack) {
    int idx = blockIdx.x * blockDim.x + threadIdx.x;
    if (idx >= NFRAGS * 64) return;
    int F = idx >> 6, cl = idx & 63, cm = cl & 15, cq = cl >> 4;
    const float* w; int IN, OUT, mt, ks, pm;
    if (F < 4)       { w = ws0; IN = 3;  OUT = 64; mt = F;            ks = 0;          pm = 0; }
    else if (F < 12) { w = ws1; IN = 64; OUT = 64; mt = (F-4) >> 1;   ks = (F-4) & 1;  pm = 1; }
    else if (F < 14) { w = ws2; IN = 64; OUT = 16; mt = 0;            ks = F - 12;     pm = 1; }
    else if (F < 18) { w = wc0; IN = 18; OUT = 64; mt = F - 14;       ks = 0;          pm = 0; }
    else if (F < 26) { w = wc1; IN = 64; OUT = 64; mt = (F-18) >> 1;  ks = (F-18) & 1; pm = 1; }
    else if (F < 34) { w = wc2; IN = 64; OUT = 64; mt = (F-26) >> 1;  ks = (F-26) & 1; pm = 1; }
    else             { w = wc3; IN = 64; OUT = 3;  mt = 0;            ks = F - 34;     pm = 1; }
    const int fo = mt * 16 + cm;
    uint32_t pk[4];
    for (int jj = 0; jj < 4; ++jj) {
        uint32_t h[2];
        for (int bb = 0; bb < 2; ++bb) {
            int kg = ks * 32 + cq * 8 + jj * 2 + bb;
            int kr = pm ? sperm(kg) : kg;
            float v = 0.f;
            if (fo < OUT && kr < IN) v = w[kr * OUT + fo];
            h[bb] = f2bf_rne(v);
        }
        pk[jj] = h[0] | (h[1] << 16);
    }
    wpack[F * 64 + cl] = make_uint4(pk[0], pk[1], pk[2], pk[3]);
}

// ---------------- main kernel ----------------
__global__ __launch_bounds__(BS, 4) void nerf_main(const float* __restrict__ xin,
                                                   const uint4* __restrict__ wpack,
                                                   float* __restrict__ outp, int n) {
    // wave-private act scratch: per (wave,tile) 16 points x 128B (64 bf16 feats),
    // 16B granules XOR-swizzled by (p&7). No __syncthreads in this kernel.
    __shared__ __align__(16) char smem[NW * T * 2048];
    const int tid = threadIdx.x, wv = tid >> 6, lane = tid & 63;
    const int p = lane & 15, q = lane >> 4;
    const int sw = p & 7;
    char* actw = smem + wv * (T * 2048);
    const int base = blockIdx.x * PTS_BLK + wv * (T * 16);

    auto aaddr = [&](int t, int g) -> char* {
        return actw + t * 2048 + p * 128 + ((g ^ sw) << 4);
    };
    auto ldA = [&](int F) -> bf16x8 {
        uint4 u = wpack[F * 64 + lane];
        return *(bf16x8*)&u;
    };
    const f32x4 z4 = {0.f, 0.f, 0.f, 0.f};

    // ---- staging: lane (p,q) stages tile q, point base+q*16+p ----
    float vv0 = 0.f, vv1 = 0.f, vv2 = 0.f;
    {
        float x0 = 0.f, x1 = 0.f, x2 = 0.f;
        const int pi = base + q * 16 + p;
        if (pi < n) {
            const float2* xp = (const float2*)(xin + (size_t)pi * 6);
            float2 a = xp[0], b = xp[1], c = xp[2];
            x0 = a.x; x1 = a.y; x2 = b.x; vv0 = b.y; vv1 = c.x; vv2 = c.y;
        }
        *(uint4*)aaddr(q, 0) = make_uint4(pk2(x0, x1), pk2(x2, 0.f), 0u, 0u);
        *(uint4*)aaddr(q, 1) = make_uint4(0u, 0u, 0u, 0u);
        *(uint4*)aaddr(q, 2) = make_uint4(0u, 0u, 0u, 0u);
        *(uint4*)aaddr(q, 3) = make_uint4(0u, 0u, 0u, 0u);
    }

    // epilogue: lane (p,q) holds feats {16mt+4q+r}; sigma-permuted storage makes
    // them contiguous 32B at granules 2q, 2q+1.
    auto storeD = [&](int t, const f32x4* d) {
        *(uint4*)aaddr(t, 2*q)   = make_uint4(pk2r(d[0][0], d[0][1]), pk2r(d[0][2], d[0][3]),
                                              pk2r(d[1][0], d[1][1]), pk2r(d[1][2], d[1][3]));
        *(uint4*)aaddr(t, 2*q+1) = make_uint4(pk2r(d[2][0], d[2][1]), pk2r(d[2][2], d[2][3]),
                                              pk2r(d[3][0], d[3][1]), pk2r(d[3][2], d[3][3]));
    };

    // ---- L0: sigma net 3->64 (K=32, frags 0..3) ----
    {
        bf16x8 A0 = ldA(0), A1 = ldA(1), A2 = ldA(2), A3 = ldA(3);
#pragma unroll
        for (int t = 0; t < T; ++t) {
            bf16x8 b = *(const bf16x8*)aaddr(t, q);
            f32x4 d[4];
            d[0] = __builtin_amdgcn_mfma_f32_16x16x32_bf16(A0, b, z4, 0, 0, 0);
            d[1] = __builtin_amdgcn_mfma_f32_16x16x32_bf16(A1, b, z4, 0, 0, 0);
            d[2] = __builtin_amdgcn_mfma_f32_16x16x32_bf16(A2, b, z4, 0, 0, 0);
            d[3] = __builtin_amdgcn_mfma_f32_16x16x32_bf16(A3, b, z4, 0, 0, 0);
            storeD(t, d);
        }
    }

    auto layer64 = [&](int FB) {
        bf16x8 A[8];
#pragma unroll
        for (int i = 0; i < 8; ++i) A[i] = ldA(FB + i);
#pragma unroll
        for (int t = 0; t < T; ++t) {
            bf16x8 b0 = *(const bf16x8*)aaddr(t, q);
            bf16x8 b1 = *(const bf16x8*)aaddr(t, 4 + q);
            f32x4 d[4];
#pragma unroll
            for (int mt = 0; mt < 4; ++mt) {
                f32x4 acc = __builtin_amdgcn_mfma_f32_16x16x32_bf16(A[mt*2],   b0, z4,  0, 0, 0);
                d[mt]     = __builtin_amdgcn_mfma_f32_16x16x32_bf16(A[mt*2+1], b1, acc, 0, 0, 0);
            }
            storeD(t, d);
        }
    };

    // ---- L1: sigma net 64->64 (frags 4..11) ----
    layer64(4);

    // ---- L2: ws2 64->16 (frags 12,13): sigma + color-input staging ----
    float sig[T];
    {
        bf16x8 A0 = ldA(12), A1 = ldA(13);
#pragma unroll
        for (int t = 0; t < T; ++t) {
            bf16x8 b0 = *(const bf16x8*)aaddr(t, q);
            bf16x8 b1 = *(const bf16x8*)aaddr(t, 4 + q);
            f32x4 acc = __builtin_amdgcn_mfma_f32_16x16x32_bf16(A0, b0, z4,  0, 0, 0);
            f32x4 d   = __builtin_amdgcn_mfma_f32_16x16x32_bf16(A1, b1, acc, 0, 0, 0);
            const float sx = d[0];                       // feat0 valid on q==0 lanes
            sig[t] = fmaxf(sx, 0.f) + __logf(1.f + __expf(-fabsf(sx)));
            // rebuild color input in-place: zero granules 0..3, then scatter
            *(uint4*)aaddr(t, q) = make_uint4(0u, 0u, 0u, 0u);
            if (q == t) {   // views of point p, tile t live on lane (p, t)
                *(uint32_t*)(aaddr(t, 0) + 0) = pk2(vv0, vv1);
                *(uint16_t*)(aaddr(t, 0) + 4) = bfu(vv2);
            }
            // geo feats f=4q+r (f>=1) -> color k=f+2
            if (q == 0) {
                *(uint16_t*)(aaddr(t, 0) + 6) = bfu(d[1]);
                *(uint32_t*)(aaddr(t, 0) + 8) = pk2(d[2], d[3]);
            } else if (q == 1) {
                *(uint32_t*)(aaddr(t, 0) + 12) = pk2(d[0], d[1]);
                *(uint32_t*)(aaddr(t, 1) + 0)  = pk2(d[2], d[3]);
            } else if (q == 2) {
                *(uint32_t*)(aaddr(t, 1) + 4) = pk2(d[0], d[1]);
                *(uint32_t*)(aaddr(t, 1) + 8) = pk2(d[2], d[3]);
            } else {
                *(uint32_t*)(aaddr(t, 1) + 12) = pk2(d[0], d[1]);
                *(uint32_t*)(aaddr(t, 2) + 0)  = pk2(d[2], d[3]);
            }
        }
    }

    // ---- L3: wc0 18->64 (K=32, frags 14..17) ----
    {
        bf16x8 A0 = ldA(14), A1 = ldA(15), A2 = ldA(16), A3 = ldA(17);
#pragma unroll
        for (int t = 0; t < T; ++t) {
            bf16x8 b = *(const bf16x8*)aaddr(t, q);
            f32x4 d[4];
            d[0] = __builtin_amdgcn_mfma_f32_16x16x32_bf16(A0, b, z4, 0, 0, 0);
            d[1] = __builtin_amdgcn_mfma_f32_16x16x32_bf16(A1, b, z4, 0, 0, 0);
            d[2] = __builtin_amdgcn_mfma_f32_16x16x32_bf16(A2, b, z4, 0, 0, 0);
            d[3] = __builtin_amdgcn_mfma_f32_16x16x32_bf16(A3, b, z4, 0, 0, 0);
            storeD(t, d);
        }
    }

    // ---- L4, L5: wc1, wc2 64->64 ----
    layer64(18);
    layer64(26);

    // ---- L6: wc3 64->3 (frags 34,35) + output ----
    {
        bf16x8 A0 = ldA(34), A1 = ldA(35);
#pragma unroll
        for (int t = 0; t < T; ++t) {
            bf16x8 b0 = *(const bf16x8*)aaddr(t, q);
            bf16x8 b1 = *(const bf16x8*)aaddr(t, 4 + q);
            f32x4 acc = __builtin_amdgcn_mfma_f32_16x16x32_bf16(A0, b0, z4,  0, 0, 0);
            f32x4 d   = __builtin_amdgcn_mfma_f32_16x16x32_bf16(A1, b1, acc, 0, 0, 0);
            if (q == 0) {
                const int pt = base + t * 16 + p;
                if (pt < n)
                    *(float4*)(outp + (size_t)pt * 4) = make_float4(d[0], d[1], d[2], sig[t]);
            }
        }
    }
}

extern "C" void kernel_launch(void* const* d_in, const int* in_sizes, int n_in,
                              void* d_out, int out_size, void* d_ws, size_t ws_size,
                              hipStream_t stream) {
    const float* x   = (const float*)d_in[0];
    const float* ws0 = (const float*)d_in[1];
    const float* ws1 = (const float*)d_in[2];
    const float* ws2 = (const float*)d_in[3];
    const float* wc0 = (const float*)d_in[4];
    const float* wc1 = (const float*)d_in[5];
    const float* wc2 = (const float*)d_in[6];
    const float* wc3 = (const float*)d_in[7];
    float* out = (float*)d_out;
    uint4* wpack = (uint4*)d_ws;

    const int n = in_sizes[0] / 6;
    pack_weights<<<(NFRAGS * 64 + 255) / 256, 256, 0, stream>>>(ws0, ws1, ws2, wc0, wc1, wc2, wc3, wpack);
    const int grid = (n + PTS_BLK - 1) / PTS_BLK;
    nerf_main<<<grid, BS, 0, stream>>>(x, wpack, out, n);
}